// Round 7
// baseline (457.418 us; speedup 1.0000x reference)
//
#include <hip/hip_runtime.h>
#include <hip/hip_bf16.h>

// Problem constants: IN=512, OUT=512, H=8, B=4, FH=64
#define KDIM 512
#define ODIM 512
#define NB 4
#define NH 8
#define FH 64
#define BFH 256   // B*FH
#define HB 32     // H*B
#define NCAT 896  // 256 bases | 32 comb | 512 res | 96 pad
#define COL_W 256 // weight col offset in Cb
#define COL_R 288 // residual col offset in Cb
#define LN_EPS 1e-5f
#define SCAN_BLK 1024   // elements per scan block

typedef __attribute__((ext_vector_type(8))) short short8;
typedef __attribute__((ext_vector_type(4))) float floatx4;

__device__ __forceinline__ float b2f(unsigned short u) {
    union { unsigned int i; float f; } v; v.i = ((unsigned int)u) << 16; return v.f;
}
__device__ __forceinline__ unsigned short f2b(float f) {
    __hip_bfloat16 h = __float2bfloat16(f);
    return *(unsigned short*)&h;
}
__device__ __forceinline__ void async16(const void* g, void* l) {
    __builtin_amdgcn_global_load_lds(
        (__attribute__((address_space(1))) unsigned int*)(g),
        (__attribute__((address_space(3))) unsigned int*)(l),
        16, 0, 0);
}

// ---- hierarchical scan: sums -> base scan -> write -----------------------
__global__ __launch_bounds__(256) void scan_sums_kernel(
        const int* __restrict__ deg, int* __restrict__ sums, int N) {
    int t = threadIdx.x;
    int idx = blockIdx.x * SCAN_BLK + t * 4;
    int4 v = {0, 0, 0, 0};
    if (idx + 3 < N) v = *(const int4*)(deg + idx);
    else {
        if (idx < N)     v.x = deg[idx];
        if (idx + 1 < N) v.y = deg[idx + 1];
        if (idx + 2 < N) v.z = deg[idx + 2];
        if (idx + 3 < N) v.w = deg[idx + 3];
    }
    int s = v.x + v.y + v.z + v.w;
    #pragma unroll
    for (int o = 32; o > 0; o >>= 1) s += __shfl_down(s, o, 64);
    __shared__ int ws[4];
    int lane = t & 63, w = t >> 6;
    if (lane == 0) ws[w] = s;
    __syncthreads();
    if (t == 0) sums[blockIdx.x] = ws[0] + ws[1] + ws[2] + ws[3];
}

// single small block: exclusive scan of sums[nb] in place (nb <= 1024)
__global__ __launch_bounds__(1024) void scan_base_kernel(
        int* __restrict__ sums, int nb) {
    __shared__ int sm[1024];
    int t = threadIdx.x;
    int own = (t < nb) ? sums[t] : 0;
    sm[t] = own;
    __syncthreads();
    for (int o = 1; o < 1024; o <<= 1) {
        int u = (t >= o) ? sm[t - o] : 0;
        __syncthreads();
        sm[t] += u;
        __syncthreads();
    }
    if (t < nb) sums[t] = sm[t] - own;   // exclusive base per block
}

__global__ __launch_bounds__(256) void scan_write_kernel(
        const int* __restrict__ deg, const int* __restrict__ bases,
        int* __restrict__ offsets, int* __restrict__ woff,
        float* __restrict__ dinv, int N, int E) {
    int t = threadIdx.x;
    int idx = blockIdx.x * SCAN_BLK + t * 4;
    int4 v = {0, 0, 0, 0};
    if (idx + 3 < N) v = *(const int4*)(deg + idx);
    else {
        if (idx < N)     v.x = deg[idx];
        if (idx + 1 < N) v.y = deg[idx + 1];
        if (idx + 2 < N) v.z = deg[idx + 2];
        if (idx + 3 < N) v.w = deg[idx + 3];
    }
    int s = v.x + v.y + v.z + v.w;
    __shared__ int sm[256];
    sm[t] = s;
    __syncthreads();
    for (int o = 1; o < 256; o <<= 1) {
        int u = (t >= o) ? sm[t - o] : 0;
        __syncthreads();
        sm[t] += u;
        __syncthreads();
    }
    int o0 = sm[t] - s + bases[blockIdx.x];
    int o1 = o0 + v.x, o2 = o1 + v.y, o3 = o2 + v.z;
    if (idx + 3 < N) {
        int4 ov = {o0, o1, o2, o3};
        *(int4*)(offsets + idx) = ov;
        *(int4*)(woff + idx) = ov;
        float4 dv = {rsqrtf((float)v.x + 1.0f), rsqrtf((float)v.y + 1.0f),
                     rsqrtf((float)v.z + 1.0f), rsqrtf((float)v.w + 1.0f)};
        *(float4*)(dinv + idx) = dv;
    } else {
        int oo[4] = {o0, o1, o2, o3};
        int vv[4] = {v.x, v.y, v.z, v.w};
        for (int j = 0; j < 4; j++) {
            if (idx + j < N) {
                offsets[idx + j] = oo[j];
                woff[idx + j] = oo[j];
                dinv[idx + j] = rsqrtf((float)vv[j] + 1.0f);
            }
        }
    }
    if (blockIdx.x == 0 && t == 0) offsets[N] = E;
}

__global__ void fill_kernel(const int* __restrict__ src, const int* __restrict__ dst,
                            int* __restrict__ woff, int* __restrict__ ebuf, int E) {
    int i = blockIdx.x * blockDim.x + threadIdx.x;
    if (i < E) {
        int pos = atomicAdd(&woff[dst[i]], 1);
        ebuf[pos] = src[i];
    }
}

// ---------------------------------------------------------------------------
// Fused: x fp32->bf16  AND  WcatT [896][512] bf16 staging + bias_cat AND deg
// histogram (three independent grid segments in one launch).
__global__ __launch_bounds__(256) void prep_kernel(
        const float* __restrict__ x, unsigned short* __restrict__ xb, long total4,
        int nCvtBlocks, int nStageBlocks,
        const float* __restrict__ Wb, const float* __restrict__ Wc,
        const float* __restrict__ Wr, const float* __restrict__ bcomb,
        const float* __restrict__ bres,
        unsigned short* __restrict__ wT, float* __restrict__ bias_cat,
        const int* __restrict__ dst, int* __restrict__ deg, int E) {
    int blk = blockIdx.x;
    if (blk < nCvtBlocks) {
        long i = (long)blk * 256 + threadIdx.x;
        if (i >= total4) return;
        float4 v = ((const float4*)x)[i];
        ushort4 u;
        u.x = f2b(v.x); u.y = f2b(v.y); u.z = f2b(v.z); u.w = f2b(v.w);
        ((ushort4*)xb)[i] = u;
    } else if (blk < nCvtBlocks + nStageBlocks) {
        int idx = (blk - nCvtBlocks) * 256 + threadIdx.x;
        if (idx >= NCAT * KDIM) return;
        int c = idx >> 9, k = idx & (KDIM - 1);
        float v;
        if (c < BFH)                   v = Wb[(size_t)k * BFH + c];
        else if (c < COL_R)            v = Wc[(size_t)k * HB + (c - COL_W)];
        else if (c < COL_R + ODIM)     v = Wr[(size_t)k * ODIM + (c - COL_R)];
        else                           v = 0.0f;
        wT[(size_t)c * KDIM + k] = f2b(v);
        if (k == 0) {
            float bv = 0.0f;
            if (c >= COL_W && c < COL_R)             bv = bcomb[c - COL_W];
            else if (c >= COL_R && c < COL_R + ODIM) bv = bres[c - COL_R];
            bias_cat[c] = bv;
        }
    } else {
        int i = (blk - nCvtBlocks - nStageBlocks) * 256 + threadIdx.x;
        if (i < E) atomicAdd(&deg[dst[i]], 1);
    }
}

// ---------------------------------------------------------------------------
// bf16 MFMA GEMM: Cb[N,896] = xb[N,512] @ wT^T + bias_cat, output bf16.
// A: double-buffered LDS via global_load_lds. B: wT is 0.9 MB, L2-resident on
// every XCD (XCD-swizzled grid) -> read b-fragments DIRECTLY from global, no
// LDS staging. Halves staged bytes/barrier, LDS 32->16 KB (more blocks/CU).
#define BM 128
#define BN 128
#define BK 32
#define SLD 136   // epilogue stage row stride (ushorts)

__global__ __launch_bounds__(256) void mfma_gemm_kernel(
        const unsigned short* __restrict__ xb,   // [N,512] bf16 bits
        const unsigned short* __restrict__ wT,   // [896,512] bf16 bits
        const float* __restrict__ bias_cat,      // [896]
        unsigned short* __restrict__ Cb,         // [N,896] bf16 bits
        int N) {
    __shared__ short lds[8192];                  // As0 | As1, 4096 shorts each
    short* As0 = lds;
    short* As1 = lds + 4096;
    int t = threadIdx.x;
    int l = t & 63, w = t >> 6;
    int wr = w >> 1, wc = w & 1;
    int quad = l >> 4, m = l & 15;

    // chunked-bijective XCD swizzle (m204)
    int nwg = gridDim.x;
    int orig = blockIdx.x;
    int q = nwg >> 3, r = nwg & 7;
    int xcd = orig & 7, slot = orig >> 3;
    int wg = (xcd < r) ? (xcd * (q + 1) + slot)
                       : (r * (q + 1) + (xcd - r) * q + slot);
    int bx = wg % 7, by = wg / 7;
    int row0 = by * BM;
    int col0 = bx * BN;

    floatx4 acc[4][4];
    floatx4 zero4 = {0.f, 0.f, 0.f, 0.f};
    #pragma unroll
    for (int i = 0; i < 4; i++)
        #pragma unroll
        for (int j = 0; j < 4; j++) acc[i][j] = zero4;

    int ar0 = row0 + (w << 4) + (l >> 2);
    int ar1 = ar0 + 64;
    int kk = (l & 3) * 8;
    const unsigned short* agp0 = xb + (size_t)min(ar0, N - 1) * KDIM + kk;
    const unsigned short* agp1 = xb + (size_t)min(ar1, N - 1) * KDIM + kk;
    // B fragment pointers: lane reads wT[col0+wc*64+j*16+m][k0+quad*8 ..+7]
    const unsigned short* bq[4];
    #pragma unroll
    for (int j = 0; j < 4; j++)
        bq[j] = wT + (size_t)(col0 + wc * 64 + j * 16 + m) * KDIM + quad * 8;

    auto stage = [&](short* A, int k0) {
        async16(agp0 + k0, A + w * 512);
        async16(agp1 + k0, A + 2048 + w * 512);
    };
    auto compute = [&](const short* As, int k0) {
        short8 a[4], b[4];
        #pragma unroll
        for (int j = 0; j < 4; j++)
            b[j] = *(const short8*)(bq[j] + k0);
        #pragma unroll
        for (int i = 0; i < 4; i++)
            a[i] = *(const short8*)(As + (wr * 64 + i * 16 + m) * BK + quad * 8);
        #pragma unroll
        for (int i = 0; i < 4; i++)
            #pragma unroll
            for (int j = 0; j < 4; j++)
                acc[i][j] = __builtin_amdgcn_mfma_f32_16x16x32_bf16(
                    a[i], b[j], acc[i][j], 0, 0, 0);
    };

    // prologue
    stage(As0, 0);
    __syncthreads();

    for (int k0 = 0; k0 < KDIM; k0 += 2 * BK) {
        if (k0 + BK < KDIM) stage(As1, k0 + BK);
        compute(As0, k0);
        __syncthreads();
        if (k0 + 2 * BK < KDIM) stage(As0, k0 + 2 * BK);
        compute(As1, k0 + BK);
        __syncthreads();
    }

    float bj[4];
    #pragma unroll
    for (int j = 0; j < 4; j++) bj[j] = bias_cat[col0 + wc * 64 + j * 16 + m];

    unsigned short* stage_buf = (unsigned short*)lds;   // [32][SLD] = 8.7 KB
    #pragma unroll
    for (int i = 0; i < 4; i++) {
        __syncthreads();
        #pragma unroll
        for (int j = 0; j < 4; j++)
            #pragma unroll
            for (int r2 = 0; r2 < 4; r2++)
                stage_buf[(wr * 16 + quad * 4 + r2) * SLD + wc * 64 + j * 16 + m] =
                    f2b(acc[i][j][r2] + bj[j]);
        __syncthreads();
        #pragma unroll
        for (int u = t; u < 512; u += 256) {
            int lr = u >> 4, c8 = u & 15;
            int gr = row0 + ((lr & 16) ? 64 : 0) + i * 16 + (lr & 15);
            if (gr < N) {
                int4 v = *(const int4*)(stage_buf + lr * SLD + c8 * 8);
                *(int4*)(Cb + (size_t)gr * NCAT + col0 + c8 * 8) = v;
            }
        }
    }
}

// ---------------------------------------------------------------------------
// FUSED gather + combine + residual + LayerNorm + ReLU. One WAVE per node.
// Main loop: full groups of 8 edges, NO clamp logic. One clamped iteration
// handles the <=7-edge tail (weight-0 lanes; duplicate loads are L1 hits).
__global__ __launch_bounds__(256) void gather_combine_kernel(
        const int* __restrict__ offsets, const int* __restrict__ ebuf,
        const float* __restrict__ dinv, const unsigned short* __restrict__ Cb,
        const float* __restrict__ conv_bias, const float* __restrict__ gamma,
        const float* __restrict__ beta, float* __restrict__ out, int N) {
    __shared__ float sagg[4][BFH];               // 4 waves/block x 256 fp32
    int wave = (blockIdx.x * blockDim.x + threadIdx.x) >> 6;
    int lane = threadIdx.x & 63;
    int wib = (threadIdx.x >> 6);                // wave in block
    if (wave >= N) return;
    int n = wave;
    float di = dinv[n];
    float self = di * di;
    ushort4 u = ((const ushort4*)(Cb + (size_t)n * NCAT))[lane];
    float ax = b2f(u.x) * self, ay = b2f(u.y) * self;
    float az = b2f(u.z) * self, aw = b2f(u.w) * self;
    int e = offsets[n], end = offsets[n + 1];
    // ---- full groups of 8 (no clamping) ----
    for (; e + 8 <= end; e += 8) {
        int s0 = ebuf[e + 0], s1 = ebuf[e + 1], s2 = ebuf[e + 2], s3 = ebuf[e + 3];
        int s4 = ebuf[e + 4], s5 = ebuf[e + 5], s6 = ebuf[e + 6], s7 = ebuf[e + 7];
        float w0 = dinv[s0] * di, w1 = dinv[s1] * di;
        float w2 = dinv[s2] * di, w3 = dinv[s3] * di;
        float w4 = dinv[s4] * di, w5 = dinv[s5] * di;
        float w6 = dinv[s6] * di, w7 = dinv[s7] * di;
        ushort4 u0 = ((const ushort4*)(Cb + (size_t)s0 * NCAT))[lane];
        ushort4 u1 = ((const ushort4*)(Cb + (size_t)s1 * NCAT))[lane];
        ushort4 u2 = ((const ushort4*)(Cb + (size_t)s2 * NCAT))[lane];
        ushort4 u3 = ((const ushort4*)(Cb + (size_t)s3 * NCAT))[lane];
        ushort4 u4 = ((const ushort4*)(Cb + (size_t)s4 * NCAT))[lane];
        ushort4 u5 = ((const ushort4*)(Cb + (size_t)s5 * NCAT))[lane];
        ushort4 u6 = ((const ushort4*)(Cb + (size_t)s6 * NCAT))[lane];
        ushort4 u7 = ((const ushort4*)(Cb + (size_t)s7 * NCAT))[lane];
        ax += b2f(u0.x) * w0 + b2f(u1.x) * w1 + b2f(u2.x) * w2 + b2f(u3.x) * w3
            + b2f(u4.x) * w4 + b2f(u5.x) * w5 + b2f(u6.x) * w6 + b2f(u7.x) * w7;
        ay += b2f(u0.y) * w0 + b2f(u1.y) * w1 + b2f(u2.y) * w2 + b2f(u3.y) * w3
            + b2f(u4.y) * w4 + b2f(u5.y) * w5 + b2f(u6.y) * w6 + b2f(u7.y) * w7;
        az += b2f(u0.z) * w0 + b2f(u1.z) * w1 + b2f(u2.z) * w2 + b2f(u3.z) * w3
            + b2f(u4.z) * w4 + b2f(u5.z) * w5 + b2f(u6.z) * w6 + b2f(u7.z) * w7;
        aw += b2f(u0.w) * w0 + b2f(u1.w) * w1 + b2f(u2.w) * w2 + b2f(u3.w) * w3
            + b2f(u4.w) * w4 + b2f(u5.w) * w5 + b2f(u6.w) * w6 + b2f(u7.w) * w7;
    }
    // ---- one clamped tail iteration (<=7 edges) ----
    if (e < end) {
        int last = end - 1;
        int s0 = ebuf[min(e + 0, last)], s1 = ebuf[min(e + 1, last)];
        int s2 = ebuf[min(e + 2, last)], s3 = ebuf[min(e + 3, last)];
        int s4 = ebuf[min(e + 4, last)], s5 = ebuf[min(e + 5, last)];
        int s6 = ebuf[min(e + 6, last)], s7 = ebuf[min(e + 7, last)];
        float w0 = (e + 0 < end) ? dinv[s0] * di : 0.0f;
        float w1 = (e + 1 < end) ? dinv[s1] * di : 0.0f;
        float w2 = (e + 2 < end) ? dinv[s2] * di : 0.0f;
        float w3 = (e + 3 < end) ? dinv[s3] * di : 0.0f;
        float w4 = (e + 4 < end) ? dinv[s4] * di : 0.0f;
        float w5 = (e + 5 < end) ? dinv[s5] * di : 0.0f;
        float w6 = (e + 6 < end) ? dinv[s6] * di : 0.0f;
        float w7 = (e + 7 < end) ? dinv[s7] * di : 0.0f;
        ushort4 u0 = ((const ushort4*)(Cb + (size_t)s0 * NCAT))[lane];
        ushort4 u1 = ((const ushort4*)(Cb + (size_t)s1 * NCAT))[lane];
        ushort4 u2 = ((const ushort4*)(Cb + (size_t)s2 * NCAT))[lane];
        ushort4 u3 = ((const ushort4*)(Cb + (size_t)s3 * NCAT))[lane];
        ushort4 u4 = ((const ushort4*)(Cb + (size_t)s4 * NCAT))[lane];
        ushort4 u5 = ((const ushort4*)(Cb + (size_t)s5 * NCAT))[lane];
        ushort4 u6 = ((const ushort4*)(Cb + (size_t)s6 * NCAT))[lane];
        ushort4 u7 = ((const ushort4*)(Cb + (size_t)s7 * NCAT))[lane];
        ax += b2f(u0.x) * w0 + b2f(u1.x) * w1 + b2f(u2.x) * w2 + b2f(u3.x) * w3
            + b2f(u4.x) * w4 + b2f(u5.x) * w5 + b2f(u6.x) * w6 + b2f(u7.x) * w7;
        ay += b2f(u0.y) * w0 + b2f(u1.y) * w1 + b2f(u2.y) * w2 + b2f(u3.y) * w3
            + b2f(u4.y) * w4 + b2f(u5.y) * w5 + b2f(u6.y) * w6 + b2f(u7.y) * w7;
        az += b2f(u0.z) * w0 + b2f(u1.z) * w1 + b2f(u2.z) * w2 + b2f(u3.z) * w3
            + b2f(u4.z) * w4 + b2f(u5.z) * w5 + b2f(u6.z) * w6 + b2f(u7.z) * w7;
        aw += b2f(u0.w) * w0 + b2f(u1.w) * w1 + b2f(u2.w) * w2 + b2f(u3.w) * w3
            + b2f(u4.w) * w4 + b2f(u5.w) * w5 + b2f(u6.w) * w6 + b2f(u7.w) * w7;
    }
    // publish this wave's agg row to its LDS slice (cols 4*lane..4*lane+3)
    float4 av = {ax, ay, az, aw};
    *(float4*)(&sagg[wib][lane * 4]) = av;

    // ---- combine tail: lane owns outputs t0 = lane*8 .. lane*8+7 ----
    int h = lane >> 3;
    int f0 = (lane & 7) * 8;
    int t0 = lane * 8;
    const unsigned short* crow = Cb + (size_t)n * NCAT;
    ushort4 wu = *(const ushort4*)(crow + COL_W + h * 4);
    float cw0 = b2f(wu.x), cw1 = b2f(wu.y), cw2 = b2f(wu.z), cw3 = b2f(wu.w);

    float4 b0a = *(const float4*)(&sagg[wib][0 * FH + f0]);
    float4 b0b = *(const float4*)(&sagg[wib][0 * FH + f0 + 4]);
    float4 b1a = *(const float4*)(&sagg[wib][1 * FH + f0]);
    float4 b1b = *(const float4*)(&sagg[wib][1 * FH + f0 + 4]);
    float4 b2a = *(const float4*)(&sagg[wib][2 * FH + f0]);
    float4 b2b = *(const float4*)(&sagg[wib][2 * FH + f0 + 4]);
    float4 b3a = *(const float4*)(&sagg[wib][3 * FH + f0]);
    float4 b3b = *(const float4*)(&sagg[wib][3 * FH + f0 + 4]);
    float a0[8] = {b0a.x, b0a.y, b0a.z, b0a.w, b0b.x, b0b.y, b0b.z, b0b.w};
    float a1[8] = {b1a.x, b1a.y, b1a.z, b1a.w, b1b.x, b1b.y, b1b.z, b1b.w};
    float a2[8] = {b2a.x, b2a.y, b2a.z, b2a.w, b2b.x, b2b.y, b2b.z, b2b.w};
    float a3[8] = {b3a.x, b3a.y, b3a.z, b3a.w, b3b.x, b3b.y, b3b.z, b3b.w};

    short8 rv = *(const short8*)(crow + COL_R + t0);
    float4 cb0 = *(const float4*)(conv_bias + t0);
    float4 cb1 = *(const float4*)(conv_bias + t0 + 4);
    float cb[8] = {cb0.x, cb0.y, cb0.z, cb0.w, cb1.x, cb1.y, cb1.z, cb1.w};

    float v[8];
    float s = 0.f, s2 = 0.f;
    #pragma unroll
    for (int j = 0; j < 8; j++) {
        float conv = cw0 * a0[j] + cw1 * a1[j] + cw2 * a2[j] + cw3 * a3[j];
        float val = conv + cb[j] + b2f((unsigned short)rv[j]);
        v[j] = val;
        s += val;
        s2 += val * val;
    }
    #pragma unroll
    for (int o = 32; o > 0; o >>= 1) {
        s  += __shfl_xor(s, o, 64);
        s2 += __shfl_xor(s2, o, 64);
    }
    float mu = s * (1.0f / (float)ODIM);
    float var = s2 * (1.0f / (float)ODIM) - mu * mu;
    float rstd = rsqrtf(var + LN_EPS);

    float4 g0 = *(const float4*)(gamma + t0);
    float4 g1 = *(const float4*)(gamma + t0 + 4);
    float4 be0 = *(const float4*)(beta + t0);
    float4 be1 = *(const float4*)(beta + t0 + 4);
    float g[8] = {g0.x, g0.y, g0.z, g0.w, g1.x, g1.y, g1.z, g1.w};
    float be[8] = {be0.x, be0.y, be0.z, be0.w, be1.x, be1.y, be1.z, be1.w};

    float ov[8];
    #pragma unroll
    for (int j = 0; j < 8; j++) {
        float o = (v[j] - mu) * rstd * g[j] + be[j];
        ov[j] = fmaxf(o, 0.0f);
    }
    float4* op = (float4*)(out + (size_t)n * ODIM + t0);
    op[0] = make_float4(ov[0], ov[1], ov[2], ov[3]);
    op[1] = make_float4(ov[4], ov[5], ov[6], ov[7]);
}

// ---------------------------------------------------------------------------
static inline char* ws_alloc(char*& p, size_t bytes) {
    char* r = p;
    p += (bytes + 255) & ~(size_t)255;
    return r;
}

extern "C" void kernel_launch(void* const* d_in, const int* in_sizes, int n_in,
                              void* d_out, int out_size, void* d_ws, size_t ws_size,
                              hipStream_t stream) {
    const float* x         = (const float*)d_in[0];
    const int*   ei        = (const int*)d_in[1];
    const float* W_bases   = (const float*)d_in[2];
    const float* W_comb    = (const float*)d_in[3];
    const float* b_comb    = (const float*)d_in[4];
    const float* conv_bias = (const float*)d_in[5];
    const float* W_res     = (const float*)d_in[6];
    const float* b_res     = (const float*)d_in[7];
    const float* gamma     = (const float*)d_in[8];
    const float* beta      = (const float*)d_in[9];

    int N = in_sizes[0] / KDIM;
    int E = in_sizes[1] / 2;
    const int* src = ei;
    const int* dst = ei + E;
    int nScanBlocks = (N + SCAN_BLK - 1) / SCAN_BLK;

    char* p = (char*)d_ws;
    int*   deg      = (int*)ws_alloc(p, sizeof(int) * (size_t)N);
    int*   offsets  = (int*)ws_alloc(p, sizeof(int) * (size_t)(N + 1));
    int*   woff     = (int*)ws_alloc(p, sizeof(int) * (size_t)N);
    int*   ebuf     = (int*)ws_alloc(p, sizeof(int) * (size_t)E);
    int*   sums     = (int*)ws_alloc(p, sizeof(int) * (size_t)nScanBlocks);
    float* dinv     = (float*)ws_alloc(p, sizeof(float) * (size_t)N);
    float* bias_cat = (float*)ws_alloc(p, sizeof(float) * NCAT);
    unsigned short* Cb  = (unsigned short*)ws_alloc(p, 2ull * N * NCAT);
    unsigned short* xb  = (unsigned short*)ws_alloc(p, 2ull * N * KDIM);
    unsigned short* wT  = (unsigned short*)ws_alloc(p, 2ull * NCAT * KDIM);
    float* out = (float*)d_out;

    hipMemsetAsync(deg, 0, sizeof(int) * (size_t)N, stream);

    // conversions + weight staging + deg histogram (one fused launch)
    long total4 = (long)N * KDIM / 4;
    int nCvtBlocks = (int)((total4 + 255) / 256);
    int nStageBlocks = (NCAT * KDIM + 255) / 256;
    int nDegBlocks = (E + 255) / 256;
    prep_kernel<<<nCvtBlocks + nStageBlocks + nDegBlocks, 256, 0, stream>>>(
        x, xb, total4, nCvtBlocks, nStageBlocks, W_bases, W_comb, W_res,
        b_comb, b_res, wT, bias_cat, dst, deg, E);

    // graph prep: hierarchical scan -> fill
    scan_sums_kernel<<<nScanBlocks, 256, 0, stream>>>(deg, sums, N);
    scan_base_kernel<<<1, 1024, 0, stream>>>(sums, nScanBlocks);
    scan_write_kernel<<<nScanBlocks, 256, 0, stream>>>(deg, sums, offsets, woff,
                                                       dinv, N, E);
    fill_kernel<<<(E + 255) / 256, 256, 0, stream>>>(src, dst, woff, ebuf, E);

    // fused MFMA GEMM -> Cb (flat grid, kernel-side swizzle)
    int nYB = (N + BM - 1) / BM;
    mfma_gemm_kernel<<<7 * nYB, 256, 0, stream>>>(xb, wT, bias_cat, Cb, N);

    // fused aggregate + combine + LN + ReLU
    gather_combine_kernel<<<(N + 3) / 4, 256, 0, stream>>>(
        offsets, ebuf, dinv, Cb, conv_bias, gamma, beta, out, N);
}

// Round 8
// 419.563 us; speedup vs baseline: 1.0902x; 1.0902x over previous
//
#include <hip/hip_runtime.h>
#include <hip/hip_bf16.h>

// Problem constants: IN=512, OUT=512, H=8, B=4, FH=64
#define KDIM 512
#define ODIM 512
#define NB 4
#define NH 8
#define FH 64
#define BFH 256   // B*FH
#define HB 32     // H*B
#define NCAT 896  // 256 bases | 32 comb | 512 res | 96 pad
#define COL_W 256 // weight col offset in Cb
#define COL_R 288 // residual col offset in Cb
#define LN_EPS 1e-5f
#define SCAN_BLK 1024   // elements per scan block

typedef __attribute__((ext_vector_type(8))) short short8;
typedef __attribute__((ext_vector_type(4))) float floatx4;

__device__ __forceinline__ float b2f(unsigned short u) {
    union { unsigned int i; float f; } v; v.i = ((unsigned int)u) << 16; return v.f;
}
__device__ __forceinline__ unsigned short f2b(float f) {
    __hip_bfloat16 h = __float2bfloat16(f);
    return *(unsigned short*)&h;
}
__device__ __forceinline__ void async16(const void* g, void* l) {
    __builtin_amdgcn_global_load_lds(
        (__attribute__((address_space(1))) unsigned int*)(g),
        (__attribute__((address_space(3))) unsigned int*)(l),
        16, 0, 0);
}

// ---- hierarchical scan: sums -> base scan -> write -----------------------
__global__ __launch_bounds__(256) void scan_sums_kernel(
        const int* __restrict__ deg, int* __restrict__ sums, int N) {
    int t = threadIdx.x;
    int idx = blockIdx.x * SCAN_BLK + t * 4;
    int4 v = {0, 0, 0, 0};
    if (idx + 3 < N) v = *(const int4*)(deg + idx);
    else {
        if (idx < N)     v.x = deg[idx];
        if (idx + 1 < N) v.y = deg[idx + 1];
        if (idx + 2 < N) v.z = deg[idx + 2];
        if (idx + 3 < N) v.w = deg[idx + 3];
    }
    int s = v.x + v.y + v.z + v.w;
    #pragma unroll
    for (int o = 32; o > 0; o >>= 1) s += __shfl_down(s, o, 64);
    __shared__ int ws[4];
    int lane = t & 63, w = t >> 6;
    if (lane == 0) ws[w] = s;
    __syncthreads();
    if (t == 0) sums[blockIdx.x] = ws[0] + ws[1] + ws[2] + ws[3];
}

// single small block: exclusive scan of sums[nb] in place (nb <= 1024)
__global__ __launch_bounds__(1024) void scan_base_kernel(
        int* __restrict__ sums, int nb) {
    __shared__ int sm[1024];
    int t = threadIdx.x;
    int own = (t < nb) ? sums[t] : 0;
    sm[t] = own;
    __syncthreads();
    for (int o = 1; o < 1024; o <<= 1) {
        int u = (t >= o) ? sm[t - o] : 0;
        __syncthreads();
        sm[t] += u;
        __syncthreads();
    }
    if (t < nb) sums[t] = sm[t] - own;   // exclusive base per block
}

__global__ __launch_bounds__(256) void scan_write_kernel(
        const int* __restrict__ deg, const int* __restrict__ bases,
        int* __restrict__ offsets, int* __restrict__ woff,
        float* __restrict__ dinv, int N, int E) {
    int t = threadIdx.x;
    int idx = blockIdx.x * SCAN_BLK + t * 4;
    int4 v = {0, 0, 0, 0};
    if (idx + 3 < N) v = *(const int4*)(deg + idx);
    else {
        if (idx < N)     v.x = deg[idx];
        if (idx + 1 < N) v.y = deg[idx + 1];
        if (idx + 2 < N) v.z = deg[idx + 2];
        if (idx + 3 < N) v.w = deg[idx + 3];
    }
    int s = v.x + v.y + v.z + v.w;
    __shared__ int sm[256];
    sm[t] = s;
    __syncthreads();
    for (int o = 1; o < 256; o <<= 1) {
        int u = (t >= o) ? sm[t - o] : 0;
        __syncthreads();
        sm[t] += u;
        __syncthreads();
    }
    int o0 = sm[t] - s + bases[blockIdx.x];
    int o1 = o0 + v.x, o2 = o1 + v.y, o3 = o2 + v.z;
    if (idx + 3 < N) {
        int4 ov = {o0, o1, o2, o3};
        *(int4*)(offsets + idx) = ov;
        *(int4*)(woff + idx) = ov;
        float4 dv = {rsqrtf((float)v.x + 1.0f), rsqrtf((float)v.y + 1.0f),
                     rsqrtf((float)v.z + 1.0f), rsqrtf((float)v.w + 1.0f)};
        *(float4*)(dinv + idx) = dv;
    } else {
        int oo[4] = {o0, o1, o2, o3};
        int vv[4] = {v.x, v.y, v.z, v.w};
        for (int j = 0; j < 4; j++) {
            if (idx + j < N) {
                offsets[idx + j] = oo[j];
                woff[idx + j] = oo[j];
                dinv[idx + j] = rsqrtf((float)vv[j] + 1.0f);
            }
        }
    }
    if (blockIdx.x == 0 && t == 0) offsets[N] = E;
}

__global__ void fill_kernel(const int* __restrict__ src, const int* __restrict__ dst,
                            int* __restrict__ woff, int* __restrict__ ebuf, int E) {
    int i = blockIdx.x * blockDim.x + threadIdx.x;
    if (i < E) {
        int pos = atomicAdd(&woff[dst[i]], 1);
        ebuf[pos] = src[i];
    }
}

// ---------------------------------------------------------------------------
// Fused: x fp32->bf16  AND  WcatT [896][512] bf16 staging + bias_cat AND deg
// histogram (three independent grid segments in one launch).
__global__ __launch_bounds__(256) void prep_kernel(
        const float* __restrict__ x, unsigned short* __restrict__ xb, long total4,
        int nCvtBlocks, int nStageBlocks,
        const float* __restrict__ Wb, const float* __restrict__ Wc,
        const float* __restrict__ Wr, const float* __restrict__ bcomb,
        const float* __restrict__ bres,
        unsigned short* __restrict__ wT, float* __restrict__ bias_cat,
        const int* __restrict__ dst, int* __restrict__ deg, int E) {
    int blk = blockIdx.x;
    if (blk < nCvtBlocks) {
        long i = (long)blk * 256 + threadIdx.x;
        if (i >= total4) return;
        float4 v = ((const float4*)x)[i];
        ushort4 u;
        u.x = f2b(v.x); u.y = f2b(v.y); u.z = f2b(v.z); u.w = f2b(v.w);
        ((ushort4*)xb)[i] = u;
    } else if (blk < nCvtBlocks + nStageBlocks) {
        int idx = (blk - nCvtBlocks) * 256 + threadIdx.x;
        if (idx >= NCAT * KDIM) return;
        int c = idx >> 9, k = idx & (KDIM - 1);
        float v;
        if (c < BFH)                   v = Wb[(size_t)k * BFH + c];
        else if (c < COL_R)            v = Wc[(size_t)k * HB + (c - COL_W)];
        else if (c < COL_R + ODIM)     v = Wr[(size_t)k * ODIM + (c - COL_R)];
        else                           v = 0.0f;
        wT[(size_t)c * KDIM + k] = f2b(v);
        if (k == 0) {
            float bv = 0.0f;
            if (c >= COL_W && c < COL_R)             bv = bcomb[c - COL_W];
            else if (c >= COL_R && c < COL_R + ODIM) bv = bres[c - COL_R];
            bias_cat[c] = bv;
        }
    } else {
        int i = (blk - nCvtBlocks - nStageBlocks) * 256 + threadIdx.x;
        if (i < E) atomicAdd(&deg[dst[i]], 1);
    }
}

// ---------------------------------------------------------------------------
// bf16 MFMA GEMM: Cb[N,896] = xb[N,512] @ wT^T + bias_cat, output bf16.
// LDS-staged A AND B (double-buffered) + XCD swizzle + XOR bank swizzle:
// global SOURCE col-block is pre-swizzled (kk = (p ^ (row&3))*8) so the
// linear global_load_lds dest yields LDS[row][p] = global[row][p^(row&3)];
// ds_read applies the same XOR (quad ^ (m&3)). Within each 16-lane b128
// phase this spreads 2 granules -> 4, killing the 4-way conflict.
#define BM 128
#define BN 128
#define BK 32
#define SLD 136   // epilogue stage row stride (ushorts)

__global__ __launch_bounds__(256) void mfma_gemm_kernel(
        const unsigned short* __restrict__ xb,   // [N,512] bf16 bits
        const unsigned short* __restrict__ wT,   // [896,512] bf16 bits
        const float* __restrict__ bias_cat,      // [896]
        unsigned short* __restrict__ Cb,         // [N,896] bf16 bits
        int N) {
    __shared__ short lds[16384];                 // As0|Bs0|As1|Bs1, 4096 shorts each
    short* As0 = lds;
    short* Bs0 = lds + 4096;
    short* As1 = lds + 8192;
    short* Bs1 = lds + 12288;
    int t = threadIdx.x;
    int l = t & 63, w = t >> 6;
    int wr = w >> 1, wc = w & 1;
    int quad = l >> 4, m = l & 15;

    // chunked-bijective XCD swizzle (m204)
    int nwg = gridDim.x;
    int orig = blockIdx.x;
    int q = nwg >> 3, r = nwg & 7;
    int xcd = orig & 7, slot = orig >> 3;
    int wg = (xcd < r) ? (xcd * (q + 1) + slot)
                       : (r * (q + 1) + (xcd - r) * q + slot);
    int bx = wg % 7, by = wg / 7;
    int row0 = by * BM;
    int col0 = bx * BN;

    floatx4 acc[4][4];
    floatx4 zero4 = {0.f, 0.f, 0.f, 0.f};
    #pragma unroll
    for (int i = 0; i < 4; i++)
        #pragma unroll
        for (int j = 0; j < 4; j++) acc[i][j] = zero4;

    int ar0 = row0 + (w << 4) + (l >> 2);
    int ar1 = ar0 + 64;
    int brow = col0 + (w << 4) + (l >> 2);
    // XOR-swizzled source column block: slot p=(l&3) holds global block
    // p ^ (row_local & 3), row_local = l>>2.
    int kk = (((l & 3) ^ ((l >> 2) & 3)) * 8);
    const unsigned short* agp0 = xb + (size_t)min(ar0, N - 1) * KDIM + kk;
    const unsigned short* agp1 = xb + (size_t)min(ar1, N - 1) * KDIM + kk;
    const unsigned short* bgp0 = wT + (size_t)brow * KDIM + kk;
    const unsigned short* bgp1 = bgp0 + (size_t)64 * KDIM;

    auto stage = [&](short* A, short* B, int k0) {
        async16(agp0 + k0, A + w * 512);
        async16(agp1 + k0, A + 2048 + w * 512);
        async16(bgp0 + k0, B + w * 512);
        async16(bgp1 + k0, B + 2048 + w * 512);
    };
    auto compute = [&](const short* As, const short* Bs) {
        int qs = (quad ^ (m & 3)) * 8;           // swizzled read position
        short8 a[4], b[4];
        #pragma unroll
        for (int i = 0; i < 4; i++)
            a[i] = *(const short8*)(As + (wr * 64 + i * 16 + m) * BK + qs);
        #pragma unroll
        for (int j = 0; j < 4; j++)
            b[j] = *(const short8*)(Bs + (wc * 64 + j * 16 + m) * BK + qs);
        #pragma unroll
        for (int i = 0; i < 4; i++)
            #pragma unroll
            for (int j = 0; j < 4; j++)
                acc[i][j] = __builtin_amdgcn_mfma_f32_16x16x32_bf16(
                    a[i], b[j], acc[i][j], 0, 0, 0);
    };

    // prologue: stage tile 0, drain, barrier
    stage(As0, Bs0, 0);
    __syncthreads();

    for (int k0 = 0; k0 < KDIM; k0 += 2 * BK) {
        if (k0 + BK < KDIM) stage(As1, Bs1, k0 + BK);
        compute(As0, Bs0);
        __syncthreads();
        if (k0 + 2 * BK < KDIM) stage(As0, Bs0, k0 + 2 * BK);
        compute(As1, Bs1);
        __syncthreads();
    }

    float bj[4];
    #pragma unroll
    for (int j = 0; j < 4; j++) bj[j] = bias_cat[col0 + wc * 64 + j * 16 + m];

    unsigned short* stage_buf = (unsigned short*)lds;   // [32][SLD]
    #pragma unroll
    for (int i = 0; i < 4; i++) {
        __syncthreads();
        #pragma unroll
        for (int j = 0; j < 4; j++)
            #pragma unroll
            for (int r2 = 0; r2 < 4; r2++)
                stage_buf[(wr * 16 + quad * 4 + r2) * SLD + wc * 64 + j * 16 + m] =
                    f2b(acc[i][j][r2] + bj[j]);
        __syncthreads();
        #pragma unroll
        for (int u = t; u < 512; u += 256) {
            int lr = u >> 4, c8 = u & 15;
            int gr = row0 + ((lr & 16) ? 64 : 0) + i * 16 + (lr & 15);
            if (gr < N) {
                int4 v = *(const int4*)(stage_buf + lr * SLD + c8 * 8);
                *(int4*)(Cb + (size_t)gr * NCAT + col0 + c8 * 8) = v;
            }
        }
    }
}

// ---------------------------------------------------------------------------
// FUSED gather + combine + residual + LayerNorm + ReLU. One WAVE per node.
// Main loop: full groups of 8 edges, NO clamp logic. One clamped iteration
// handles the <=7-edge tail (weight-0 lanes; duplicate loads are L1 hits).
__global__ __launch_bounds__(256) void gather_combine_kernel(
        const int* __restrict__ offsets, const int* __restrict__ ebuf,
        const float* __restrict__ dinv, const unsigned short* __restrict__ Cb,
        const float* __restrict__ conv_bias, const float* __restrict__ gamma,
        const float* __restrict__ beta, float* __restrict__ out, int N) {
    __shared__ float sagg[4][BFH];               // 4 waves/block x 256 fp32
    int wave = (blockIdx.x * blockDim.x + threadIdx.x) >> 6;
    int lane = threadIdx.x & 63;
    int wib = (threadIdx.x >> 6);                // wave in block
    if (wave >= N) return;
    int n = wave;
    float di = dinv[n];
    float self = di * di;
    ushort4 u = ((const ushort4*)(Cb + (size_t)n * NCAT))[lane];
    float ax = b2f(u.x) * self, ay = b2f(u.y) * self;
    float az = b2f(u.z) * self, aw = b2f(u.w) * self;
    int e = offsets[n], end = offsets[n + 1];
    // ---- full groups of 8 (no clamping) ----
    for (; e + 8 <= end; e += 8) {
        int s0 = ebuf[e + 0], s1 = ebuf[e + 1], s2 = ebuf[e + 2], s3 = ebuf[e + 3];
        int s4 = ebuf[e + 4], s5 = ebuf[e + 5], s6 = ebuf[e + 6], s7 = ebuf[e + 7];
        float w0 = dinv[s0] * di, w1 = dinv[s1] * di;
        float w2 = dinv[s2] * di, w3 = dinv[s3] * di;
        float w4 = dinv[s4] * di, w5 = dinv[s5] * di;
        float w6 = dinv[s6] * di, w7 = dinv[s7] * di;
        ushort4 u0 = ((const ushort4*)(Cb + (size_t)s0 * NCAT))[lane];
        ushort4 u1 = ((const ushort4*)(Cb + (size_t)s1 * NCAT))[lane];
        ushort4 u2 = ((const ushort4*)(Cb + (size_t)s2 * NCAT))[lane];
        ushort4 u3 = ((const ushort4*)(Cb + (size_t)s3 * NCAT))[lane];
        ushort4 u4 = ((const ushort4*)(Cb + (size_t)s4 * NCAT))[lane];
        ushort4 u5 = ((const ushort4*)(Cb + (size_t)s5 * NCAT))[lane];
        ushort4 u6 = ((const ushort4*)(Cb + (size_t)s6 * NCAT))[lane];
        ushort4 u7 = ((const ushort4*)(Cb + (size_t)s7 * NCAT))[lane];
        ax += b2f(u0.x) * w0 + b2f(u1.x) * w1 + b2f(u2.x) * w2 + b2f(u3.x) * w3
            + b2f(u4.x) * w4 + b2f(u5.x) * w5 + b2f(u6.x) * w6 + b2f(u7.x) * w7;
        ay += b2f(u0.y) * w0 + b2f(u1.y) * w1 + b2f(u2.y) * w2 + b2f(u3.y) * w3
            + b2f(u4.y) * w4 + b2f(u5.y) * w5 + b2f(u6.y) * w6 + b2f(u7.y) * w7;
        az += b2f(u0.z) * w0 + b2f(u1.z) * w1 + b2f(u2.z) * w2 + b2f(u3.z) * w3
            + b2f(u4.z) * w4 + b2f(u5.z) * w5 + b2f(u6.z) * w6 + b2f(u7.z) * w7;
        aw += b2f(u0.w) * w0 + b2f(u1.w) * w1 + b2f(u2.w) * w2 + b2f(u3.w) * w3
            + b2f(u4.w) * w4 + b2f(u5.w) * w5 + b2f(u6.w) * w6 + b2f(u7.w) * w7;
    }
    // ---- one clamped tail iteration (<=7 edges) ----
    if (e < end) {
        int last = end - 1;
        int s0 = ebuf[min(e + 0, last)], s1 = ebuf[min(e + 1, last)];
        int s2 = ebuf[min(e + 2, last)], s3 = ebuf[min(e + 3, last)];
        int s4 = ebuf[min(e + 4, last)], s5 = ebuf[min(e + 5, last)];
        int s6 = ebuf[min(e + 6, last)], s7 = ebuf[min(e + 7, last)];
        float w0 = (e + 0 < end) ? dinv[s0] * di : 0.0f;
        float w1 = (e + 1 < end) ? dinv[s1] * di : 0.0f;
        float w2 = (e + 2 < end) ? dinv[s2] * di : 0.0f;
        float w3 = (e + 3 < end) ? dinv[s3] * di : 0.0f;
        float w4 = (e + 4 < end) ? dinv[s4] * di : 0.0f;
        float w5 = (e + 5 < end) ? dinv[s5] * di : 0.0f;
        float w6 = (e + 6 < end) ? dinv[s6] * di : 0.0f;
        float w7 = (e + 7 < end) ? dinv[s7] * di : 0.0f;
        ushort4 u0 = ((const ushort4*)(Cb + (size_t)s0 * NCAT))[lane];
        ushort4 u1 = ((const ushort4*)(Cb + (size_t)s1 * NCAT))[lane];
        ushort4 u2 = ((const ushort4*)(Cb + (size_t)s2 * NCAT))[lane];
        ushort4 u3 = ((const ushort4*)(Cb + (size_t)s3 * NCAT))[lane];
        ushort4 u4 = ((const ushort4*)(Cb + (size_t)s4 * NCAT))[lane];
        ushort4 u5 = ((const ushort4*)(Cb + (size_t)s5 * NCAT))[lane];
        ushort4 u6 = ((const ushort4*)(Cb + (size_t)s6 * NCAT))[lane];
        ushort4 u7 = ((const ushort4*)(Cb + (size_t)s7 * NCAT))[lane];
        ax += b2f(u0.x) * w0 + b2f(u1.x) * w1 + b2f(u2.x) * w2 + b2f(u3.x) * w3
            + b2f(u4.x) * w4 + b2f(u5.x) * w5 + b2f(u6.x) * w6 + b2f(u7.x) * w7;
        ay += b2f(u0.y) * w0 + b2f(u1.y) * w1 + b2f(u2.y) * w2 + b2f(u3.y) * w3
            + b2f(u4.y) * w4 + b2f(u5.y) * w5 + b2f(u6.y) * w6 + b2f(u7.y) * w7;
        az += b2f(u0.z) * w0 + b2f(u1.z) * w1 + b2f(u2.z) * w2 + b2f(u3.z) * w3
            + b2f(u4.z) * w4 + b2f(u5.z) * w5 + b2f(u6.z) * w6 + b2f(u7.z) * w7;
        aw += b2f(u0.w) * w0 + b2f(u1.w) * w1 + b2f(u2.w) * w2 + b2f(u3.w) * w3
            + b2f(u4.w) * w4 + b2f(u5.w) * w5 + b2f(u6.w) * w6 + b2f(u7.w) * w7;
    }
    // publish this wave's agg row to its LDS slice (cols 4*lane..4*lane+3)
    float4 av = {ax, ay, az, aw};
    *(float4*)(&sagg[wib][lane * 4]) = av;

    // ---- combine tail: lane owns outputs t0 = lane*8 .. lane*8+7 ----
    int h = lane >> 3;
    int f0 = (lane & 7) * 8;
    int t0 = lane * 8;
    const unsigned short* crow = Cb + (size_t)n * NCAT;
    ushort4 wu = *(const ushort4*)(crow + COL_W + h * 4);
    float cw0 = b2f(wu.x), cw1 = b2f(wu.y), cw2 = b2f(wu.z), cw3 = b2f(wu.w);

    float4 b0a = *(const float4*)(&sagg[wib][0 * FH + f0]);
    float4 b0b = *(const float4*)(&sagg[wib][0 * FH + f0 + 4]);
    float4 b1a = *(const float4*)(&sagg[wib][1 * FH + f0]);
    float4 b1b = *(const float4*)(&sagg[wib][1 * FH + f0 + 4]);
    float4 b2a = *(const float4*)(&sagg[wib][2 * FH + f0]);
    float4 b2b = *(const float4*)(&sagg[wib][2 * FH + f0 + 4]);
    float4 b3a = *(const float4*)(&sagg[wib][3 * FH + f0]);
    float4 b3b = *(const float4*)(&sagg[wib][3 * FH + f0 + 4]);
    float a0[8] = {b0a.x, b0a.y, b0a.z, b0a.w, b0b.x, b0b.y, b0b.z, b0b.w};
    float a1[8] = {b1a.x, b1a.y, b1a.z, b1a.w, b1b.x, b1b.y, b1b.z, b1b.w};
    float a2[8] = {b2a.x, b2a.y, b2a.z, b2a.w, b2b.x, b2b.y, b2b.z, b2b.w};
    float a3[8] = {b3a.x, b3a.y, b3a.z, b3a.w, b3b.x, b3b.y, b3b.z, b3b.w};

    short8 rv = *(const short8*)(crow + COL_R + t0);
    float4 cb0 = *(const float4*)(conv_bias + t0);
    float4 cb1 = *(const float4*)(conv_bias + t0 + 4);
    float cb[8] = {cb0.x, cb0.y, cb0.z, cb0.w, cb1.x, cb1.y, cb1.z, cb1.w};

    float v[8];
    float s = 0.f, s2 = 0.f;
    #pragma unroll
    for (int j = 0; j < 8; j++) {
        float conv = cw0 * a0[j] + cw1 * a1[j] + cw2 * a2[j] + cw3 * a3[j];
        float val = conv + cb[j] + b2f((unsigned short)rv[j]);
        v[j] = val;
        s += val;
        s2 += val * val;
    }
    #pragma unroll
    for (int o = 32; o > 0; o >>= 1) {
        s  += __shfl_xor(s, o, 64);
        s2 += __shfl_xor(s2, o, 64);
    }
    float mu = s * (1.0f / (float)ODIM);
    float var = s2 * (1.0f / (float)ODIM) - mu * mu;
    float rstd = rsqrtf(var + LN_EPS);

    float4 g0 = *(const float4*)(gamma + t0);
    float4 g1 = *(const float4*)(gamma + t0 + 4);
    float4 be0 = *(const float4*)(beta + t0);
    float4 be1 = *(const float4*)(beta + t0 + 4);
    float g[8] = {g0.x, g0.y, g0.z, g0.w, g1.x, g1.y, g1.z, g1.w};
    float be[8] = {be0.x, be0.y, be0.z, be0.w, be1.x, be1.y, be1.z, be1.w};

    float ov[8];
    #pragma unroll
    for (int j = 0; j < 8; j++) {
        float o = (v[j] - mu) * rstd * g[j] + be[j];
        ov[j] = fmaxf(o, 0.0f);
    }
    float4* op = (float4*)(out + (size_t)n * ODIM + t0);
    op[0] = make_float4(ov[0], ov[1], ov[2], ov[3]);
    op[1] = make_float4(ov[4], ov[5], ov[6], ov[7]);
}

// ---------------------------------------------------------------------------
static inline char* ws_alloc(char*& p, size_t bytes) {
    char* r = p;
    p += (bytes + 255) & ~(size_t)255;
    return r;
}

extern "C" void kernel_launch(void* const* d_in, const int* in_sizes, int n_in,
                              void* d_out, int out_size, void* d_ws, size_t ws_size,
                              hipStream_t stream) {
    const float* x         = (const float*)d_in[0];
    const int*   ei        = (const int*)d_in[1];
    const float* W_bases   = (const float*)d_in[2];
    const float* W_comb    = (const float*)d_in[3];
    const float* b_comb    = (const float*)d_in[4];
    const float* conv_bias = (const float*)d_in[5];
    const float* W_res     = (const float*)d_in[6];
    const float* b_res     = (const float*)d_in[7];
    const float* gamma     = (const float*)d_in[8];
    const float* beta      = (const float*)d_in[9];

    int N = in_sizes[0] / KDIM;
    int E = in_sizes[1] / 2;
    const int* src = ei;
    const int* dst = ei + E;
    int nScanBlocks = (N + SCAN_BLK - 1) / SCAN_BLK;

    char* p = (char*)d_ws;
    int*   deg      = (int*)ws_alloc(p, sizeof(int) * (size_t)N);
    int*   offsets  = (int*)ws_alloc(p, sizeof(int) * (size_t)(N + 1));
    int*   woff     = (int*)ws_alloc(p, sizeof(int) * (size_t)N);
    int*   ebuf     = (int*)ws_alloc(p, sizeof(int) * (size_t)E);
    int*   sums     = (int*)ws_alloc(p, sizeof(int) * (size_t)nScanBlocks);
    float* dinv     = (float*)ws_alloc(p, sizeof(float) * (size_t)N);
    float* bias_cat = (float*)ws_alloc(p, sizeof(float) * NCAT);
    unsigned short* Cb  = (unsigned short*)ws_alloc(p, 2ull * N * NCAT);
    unsigned short* xb  = (unsigned short*)ws_alloc(p, 2ull * N * KDIM);
    unsigned short* wT  = (unsigned short*)ws_alloc(p, 2ull * NCAT * KDIM);
    float* out = (float*)d_out;

    hipMemsetAsync(deg, 0, sizeof(int) * (size_t)N, stream);

    // conversions + weight staging + deg histogram (one fused launch)
    long total4 = (long)N * KDIM / 4;
    int nCvtBlocks = (int)((total4 + 255) / 256);
    int nStageBlocks = (NCAT * KDIM + 255) / 256;
    int nDegBlocks = (E + 255) / 256;
    prep_kernel<<<nCvtBlocks + nStageBlocks + nDegBlocks, 256, 0, stream>>>(
        x, xb, total4, nCvtBlocks, nStageBlocks, W_bases, W_comb, W_res,
        b_comb, b_res, wT, bias_cat, dst, deg, E);

    // graph prep: hierarchical scan -> fill
    scan_sums_kernel<<<nScanBlocks, 256, 0, stream>>>(deg, sums, N);
    scan_base_kernel<<<1, 1024, 0, stream>>>(sums, nScanBlocks);
    scan_write_kernel<<<nScanBlocks, 256, 0, stream>>>(deg, sums, offsets, woff,
                                                       dinv, N, E);
    fill_kernel<<<(E + 255) / 256, 256, 0, stream>>>(src, dst, woff, ebuf, E);

    // fused MFMA GEMM -> Cb (flat grid, kernel-side swizzle)
    int nYB = (N + BM - 1) / BM;
    mfma_gemm_kernel<<<7 * nYB, 256, 0, stream>>>(xb, wT, bias_cat, Cb, N);

    // fused aggregate + combine + LN + ReLU
    gather_combine_kernel<<<(N + 3) / 4, 256, 0, stream>>>(
        offsets, ebuf, dinv, Cb, conv_bias, gamma, beta, out, N);
}